// Round 3
// baseline (89.571 us; speedup 1.0000x reference)
//
#include <hip/hip_runtime.h>

// ===== ROUND 3: INSTRUMENTED PROBE (not an optimization attempt) =====
// Identical per-rep work to round 2, repeated reps=16 times inside one
// dispatch. max() accumulation across reps is idempotent -> output is
// bit-identical to round 2. Purpose:
//  (a) solve dur = O_fixed + 16*K to split launch overhead vs kernel time
//  (b) push the dispatch above the harness's 39us fill kernels so it
//      appears in rocprof top-5 with real counters (VALUBusy, LDS conflicts,
//      occupancy, VGPRs).
// asm volatile memory clobber per rep prevents load-CSE/DCE across reps
// (methodology rule: ablation-via-skip DCEs upstream-dead ops).

#define N_   8
#define C_   16
#define H_   32
#define W_   32
#define O_   64
#define KH_  3
#define KW_  3
#define F_   (C_ * KH_ * KW_)     // 144
#define PADW 36                   // row stride in floats (data at cols 1..32)
#define ROWS 18                   // 16 output rows + 2 halo
#define LDSF (ROWS * C_ * PADW)   // 10368 floats = 41472 B

__global__ __launch_bounds__(256)
void normdist_kernel(const float* __restrict__ x,
                     const float* __restrict__ weight,
                     const float* __restrict__ bias,
                     float* __restrict__ out,
                     int reps)
{
    __shared__ float xs[LDSF];    // [r][c][w]
    const int tid = threadIdx.x;
    const int o0  = blockIdx.x * 2;
    const int h0  = blockIdx.y * 16;
    const int n   = blockIdx.z;

    const float* __restrict__ xn = x + (size_t)n * (C_ * H_ * W_);
    const float* __restrict__ wr = weight + (size_t)o0 * F_;   // block-uniform

    // thread -> (local row, w-pair)
    const int hl = tid >> 4;              // 0..15
    const int w0 = (tid & 15) << 1;       // 0,2,...,30

    float m[2][2];                        // [og][p], statically indexed
    m[0][0] = m[0][1] = m[1][0] = m[1][1] = 0.f;

    for (int rep = 0; rep < reps; ++rep) {
        // ---- zero the two border columns (0 and 33) ----
        for (int t = tid; t < ROWS * C_; t += 256) {
            xs[t * PADW + 0]  = 0.f;
            xs[t * PADW + 33] = 0.f;
        }

        // ---- stage 18 rows x 16 ch x 32 w (9 float4 per thread) ----
        #pragma unroll
        for (int k = 0; k < 9; ++k) {
            int idx = tid + k * 256;          // 0..2303
            int wq  = idx & 7;                // float4 index within row
            int c   = (idx >> 3) & 15;
            int r   = idx >> 7;               // 0..17
            int grow = h0 - 1 + r;            // global row incl. halo
            float4 v = make_float4(0.f, 0.f, 0.f, 0.f);
            if (grow >= 0 && grow < H_)
                v = *reinterpret_cast<const float4*>(xn + c * (H_ * W_) + grow * W_ + wq * 4);
            float* dst = &xs[(r * C_ + c) * PADW + 1 + wq * 4];
            dst[0] = v.x; dst[1] = v.y; dst[2] = v.z; dst[3] = v.w;
        }
        __syncthreads();

        #pragma unroll
        for (int cp = 0; cp < 8; ++cp) {      // channel pairs
            #pragma unroll
            for (int kh = 0; kh < KH_; ++kh) {
                const int rbase = (hl + kh) * C_;
                const float* rowA = &xs[(rbase + 2 * cp    ) * PADW + w0];
                const float* rowB = &xs[(rbase + 2 * cp + 1) * PADW + w0];
                float2 a01 = *reinterpret_cast<const float2*>(rowA);
                float2 a23 = *reinterpret_cast<const float2*>(rowA + 2);
                float2 b01 = *reinterpret_cast<const float2*>(rowB);
                float2 b23 = *reinterpret_cast<const float2*>(rowB + 2);
                float xa[4] = {a01.x, a01.y, a23.x, a23.y};
                float xb[4] = {b01.x, b01.y, b23.x, b23.y};
                const int fA = ((2 * cp    ) * KH_ + kh) * KW_;
                const int fB = ((2 * cp + 1) * KH_ + kh) * KW_;
                #pragma unroll
                for (int og = 0; og < 2; ++og) {
                    const float wA0 = wr[og * F_ + fA + 0];
                    const float wA1 = wr[og * F_ + fA + 1];
                    const float wA2 = wr[og * F_ + fA + 2];
                    const float wB0 = wr[og * F_ + fB + 0];
                    const float wB1 = wr[og * F_ + fB + 1];
                    const float wB2 = wr[og * F_ + fB + 2];
                    #pragma unroll
                    for (int p = 0; p < 2; ++p) {
                        float v0 = __builtin_fabsf(xa[p + 0] - wA0);
                        float v1 = __builtin_fabsf(xa[p + 1] - wA1);
                        float v2 = __builtin_fabsf(xa[p + 2] - wA2);
                        float v3 = __builtin_fabsf(xb[p + 0] - wB0);
                        float v4 = __builtin_fabsf(xb[p + 1] - wB1);
                        float v5 = __builtin_fabsf(xb[p + 2] - wB2);
                        float mm = m[og][p];
                        mm = fmaxf(fmaxf(mm, v0), v1);
                        mm = fmaxf(fmaxf(mm, v2), v3);
                        mm = fmaxf(fmaxf(mm, v4), v5);
                        m[og][p] = mm;
                    }
                }
            }
        }
        __syncthreads();   // reads done before next rep's staging overwrites

        // prevent cross-rep load CSE / dead-code elimination
        asm volatile("" ::: "memory");
    }

    // ---- epilogue: bias + float2 stores ----
    const float b0 = bias[o0 + 0];
    const float b1 = bias[o0 + 1];
    float* dst0 = out + ((size_t)(n * O_ + o0) * (H_ * W_)) + (h0 + hl) * W_ + w0;
    *reinterpret_cast<float2*>(dst0) = make_float2(m[0][0] + b0, m[0][1] + b0);
    float* dst1 = dst0 + H_ * W_;
    *reinterpret_cast<float2*>(dst1) = make_float2(m[1][0] + b1, m[1][1] + b1);
}

extern "C" void kernel_launch(void* const* d_in, const int* in_sizes, int n_in,
                              void* d_out, int out_size, void* d_ws, size_t ws_size,
                              hipStream_t stream) {
    const float* x  = (const float*)d_in[0];
    const float* w  = (const float*)d_in[1];
    const float* b  = (const float*)d_in[2];
    float* out      = (float*)d_out;

    dim3 grid(O_ / 2, 2, N_);   // 32 og-pairs x 2 h-halves x 8 n = 512 blocks
    dim3 block(256);
    hipLaunchKernelGGL(normdist_kernel, grid, block, 0, stream,
                       x, w, b, out, 16 /*reps: probe*/);
}

// Round 4
// 12.279 us; speedup vs baseline: 7.2946x; 7.2946x over previous
//
#include <hip/hip_runtime.h>

// NormDistConv: out[n,o,h,w] = max_f |patch(n,:,h,w)[f] - weight[o,f]| + bias[o]
// x: (8,16,32,32) f32, weight: (64,144) f32, bias: (64,) f32, out: (8,64,32,32) f32
//
// V4: grid 1024 = (32 og-pairs, 4 h-tiles, 8 n), 256 threads (4 waves).
//   wave g in 0..3 owns channels 4g..4g+3 (c-split), combined via LDS partial max.
//   thread: 2 og x 4 px. LDS x-tile [10 rows][16 ch][32 w], XOR-swizzled rows
//   (col ^ (row&3)<<3, bijective), aligned b128 writes (bank-uniform) and
//   aligned b128 reads; horizontal halo via cndmask'd b32 reads, no halo cols.

#define N_ 8
#define C_ 16
#define H_ 32
#define W_ 32
#define O_ 64
#define F_ 144
#define HT 8
#define RT (HT + 2)          // 10 staged rows

__global__ __launch_bounds__(256)
void normdist_kernel(const float* __restrict__ x,
                     const float* __restrict__ weight,
                     const float* __restrict__ bias,
                     float* __restrict__ out)
{
    __shared__ float xs[RT * C_ * 32];      // 5120 fl, row-swizzled
    __shared__ float sc[3][2][HT][W_];      // partial maxes of c-groups 1..3

    const int tid = threadIdx.x;
    const int o0  = blockIdx.x * 2;
    const int h0  = blockIdx.y * HT;
    const int n   = blockIdx.z;

    const float* __restrict__ xn = x + (size_t)n * (C_ * H_ * W_);
    const float* __restrict__ wr = weight + (size_t)o0 * F_;

    // ---- stage 10 rows x 16 ch x 32 w: 1280 float4, 5 per thread ----
    #pragma unroll
    for (int k = 0; k < 5; ++k) {
        int idx  = tid + k * 256;            // 0..1279
        int swq  = idx & 7;                  // float4 within row
        int c    = (idx >> 3) & 15;
        int r    = idx >> 7;                 // 0..9
        int grow = h0 - 1 + r;
        float4 v = make_float4(0.f, 0.f, 0.f, 0.f);
        if (grow >= 0 && grow < H_)
            v = *reinterpret_cast<const float4*>(xn + c * (H_ * W_) + grow * W_ + swq * 4);
        int sig = (r & 3) << 3;              // XOR swizzle, bijective (col<32)
        float* dst = &xs[(r * 16 + c) * 32 + ((swq * 4) ^ sig)];
        *reinterpret_cast<float4*>(dst) = v; // aligned b128: banks uniform
    }
    __syncthreads();

    const int wq = tid & 7;                  // w-quad
    const int hl = (tid >> 3) & 7;           // output row in tile
    const int g  = tid >> 6;                 // wave id = c-group
    const int w0 = wq * 4;
    const bool left_edge  = (wq == 0);
    const bool right_edge = (wq == 7);

    // force c-group base into SGPR (uniform per wave) for s_load weights
    const int cbase = __builtin_amdgcn_readfirstlane(g) * 4;

    float m[2][4];
    #pragma unroll
    for (int og = 0; og < 2; ++og)
        #pragma unroll
        for (int p = 0; p < 4; ++p)
            m[og][p] = 0.f;                  // |x-w| >= 0: safe identity

    #pragma unroll
    for (int cc = 0; cc < 4; ++cc) {
        const int c = cbase + cc;
        #pragma unroll
        for (int kh = 0; kh < 3; ++kh) {
            const int R    = hl + kh;                // staged row 0..9
            const int sig  = (R & 3) << 3;
            const int base = (R * 16 + c) * 32;
            // main 4 words, aligned b128 (w0^sig is a multiple of 4)
            float4 xm = *reinterpret_cast<const float4*>(&xs[base + (w0 ^ sig)]);
            // halo words via cndmask (lane-constant predicates)
            float xl = left_edge  ? 0.f : xs[base + ((w0 - 1) ^ sig)];
            float xr = right_edge ? 0.f : xs[base + ((w0 + 4) ^ sig)];
            float xw[6] = {xl, xm.x, xm.y, xm.z, xm.w, xr};
            const int f = c * 9 + kh * 3;
            #pragma unroll
            for (int og = 0; og < 2; ++og) {
                const float wv0 = wr[og * F_ + f + 0];
                const float wv1 = wr[og * F_ + f + 1];
                const float wv2 = wr[og * F_ + f + 2];
                #pragma unroll
                for (int p = 0; p < 4; ++p) {
                    float v0 = __builtin_fabsf(xw[p + 0] - wv0);
                    float v1 = __builtin_fabsf(xw[p + 1] - wv1);
                    float v2 = __builtin_fabsf(xw[p + 2] - wv2);
                    float mm = m[og][p];
                    mm = fmaxf(fmaxf(mm, v0), v1);   // v_max3
                    m[og][p] = fmaxf(mm, v2);
                }
            }
        }
    }

    // ---- c-split combine: groups 1..3 publish, wave 0 reduces + stores ----
    if (g > 0) {
        #pragma unroll
        for (int og = 0; og < 2; ++og)
            *reinterpret_cast<float4*>(&sc[g - 1][og][hl][w0]) =
                make_float4(m[og][0], m[og][1], m[og][2], m[og][3]);
    }
    __syncthreads();

    if (g == 0) {
        #pragma unroll
        for (int og = 0; og < 2; ++og) {
            float4 a = *reinterpret_cast<const float4*>(&sc[0][og][hl][w0]);
            float4 b = *reinterpret_cast<const float4*>(&sc[1][og][hl][w0]);
            float4 d = *reinterpret_cast<const float4*>(&sc[2][og][hl][w0]);
            const float bv = bias[o0 + og];
            float4 r;
            r.x = fmaxf(fmaxf(fmaxf(m[og][0], a.x), b.x), d.x) + bv;
            r.y = fmaxf(fmaxf(fmaxf(m[og][1], a.y), b.y), d.y) + bv;
            r.z = fmaxf(fmaxf(fmaxf(m[og][2], a.z), b.z), d.z) + bv;
            r.w = fmaxf(fmaxf(fmaxf(m[og][3], a.w), b.w), d.w) + bv;
            float* dst = out + ((size_t)(n * O_ + o0 + og) * (H_ * W_))
                             + (h0 + hl) * W_ + w0;
            *reinterpret_cast<float4*>(dst) = r;     // aligned, coalesced
        }
    }
}

extern "C" void kernel_launch(void* const* d_in, const int* in_sizes, int n_in,
                              void* d_out, int out_size, void* d_ws, size_t ws_size,
                              hipStream_t stream) {
    const float* x  = (const float*)d_in[0];
    const float* w  = (const float*)d_in[1];
    const float* b  = (const float*)d_in[2];
    float* out      = (float*)d_out;

    dim3 grid(O_ / 2, H_ / HT, N_);   // 32 x 4 x 8 = 1024 blocks
    dim3 block(256);
    hipLaunchKernelGGL(normdist_kernel, grid, block, 0, stream, x, w, b, out);
}

// Round 6
// 10.578 us; speedup vs baseline: 8.4675x; 1.1608x over previous
//
#include <hip/hip_runtime.h>

// NormDistConv: out[n,o,h,w] = max_f |patch(n,:,h,w)[f] - weight[o,f]| + bias[o]
// x: (8,16,32,32) f32, weight: (64,144) f32, bias: (64,) f32, out: (8,64,32,32) f32
//
// V6 = V5 with the horizontal halo via __shfl_up/__shfl_down (ds_bpermute,
// conflict-free, HIP-guaranteed semantics) instead of DPP (V5's failure) or
// conflicted LDS scalar reads (V4's slowdown).
//   grid 1024 = (32 og-pairs, 4 h-tiles, 8 n), 256 threads (4 waves),
//   wave g owns channels 4g..4g+3 (c-split), LDS partial-max combine.
//   LDS x-tile [c][r][36]: r-stride == 4, c-stride == 8 (mod 32) ->
//   staging b128 writes and compute b128 reads both at 8-words/bank baseline.

#define N_ 8
#define C_ 16
#define H_ 32
#define W_ 32
#define O_ 64
#define F_ 144
#define HT 8
#define RT (HT + 2)      // 10 staged rows
#define RSTR 36          // row stride in words

__global__ __launch_bounds__(256)
void normdist_kernel(const float* __restrict__ x,
                     const float* __restrict__ weight,
                     const float* __restrict__ bias,
                     float* __restrict__ out)
{
    __shared__ float xs[C_ * RT * RSTR];   // 5760 fl = 23 KB, [c][r][36]
    __shared__ float sc[3][2][HT][W_];     // partial maxes, 6 KB

    const int tid = threadIdx.x;
    const int o0  = blockIdx.x * 2;
    const int h0  = blockIdx.y * HT;
    const int n   = blockIdx.z;

    const float* __restrict__ xn = x + (size_t)n * (C_ * H_ * W_);
    const float* __restrict__ wr = weight + (size_t)o0 * F_;

    // ---- stage 16 ch x 10 rows x 32 w: 1280 float4, 5 per thread ----
    #pragma unroll
    for (int k = 0; k < 5; ++k) {
        int idx  = tid + k * 256;          // 0..1279
        int swq  = idx & 7;
        int c    = (idx >> 3) & 15;
        int r    = idx >> 7;               // 0..9
        int grow = h0 - 1 + r;
        float4 v = make_float4(0.f, 0.f, 0.f, 0.f);
        if (grow >= 0 && grow < H_)
            v = *reinterpret_cast<const float4*>(xn + c * (H_ * W_) + grow * W_ + swq * 4);
        *reinterpret_cast<float4*>(&xs[(c * RT + r) * RSTR + swq * 4]) = v;
    }
    __syncthreads();

    const int wq = tid & 7;                // w-quad
    const int hl = (tid >> 3) & 7;         // output row in tile
    const int g  = tid >> 6;               // wave id = c-group
    const int w0 = wq * 4;
    const bool left_edge  = (wq == 0);
    const bool right_edge = (wq == 7);

    const int cbase = __builtin_amdgcn_readfirstlane(g) * 4;  // SGPR-uniform

    float m[2][4];
    #pragma unroll
    for (int og = 0; og < 2; ++og)
        #pragma unroll
        for (int p = 0; p < 4; ++p)
            m[og][p] = 0.f;                // |x-w| >= 0: safe identity

    #pragma unroll
    for (int cc = 0; cc < 4; ++cc) {
        const int c = cbase + cc;
        #pragma unroll
        for (int kh = 0; kh < 3; ++kh) {
            const int R = hl + kh;         // staged row 0..9
            float4 xm = *reinterpret_cast<const float4*>(&xs[(c * RT + R) * RSTR + w0]);
            // horizontal halo from neighbor lane (same hl row):
            // lane i-1 holds quad w0-4..w0-1 -> its .w is col w0-1;
            // lane i+1 holds quad w0+4..w0+7 -> its .x is col w0+4.
            // wq==0 / wq==7 lanes (shfl clamp or cross-row) are masked to the
            // zero-pad value, which is exactly cols -1 and 32.
            float xl = __shfl_up(xm.w, 1);
            float xr = __shfl_down(xm.x, 1);
            xl = left_edge  ? 0.f : xl;
            xr = right_edge ? 0.f : xr;
            float xw[6] = {xl, xm.x, xm.y, xm.z, xm.w, xr};
            const int f = c * 9 + kh * 3;
            #pragma unroll
            for (int og = 0; og < 2; ++og) {
                const float wv0 = wr[og * F_ + f + 0];
                const float wv1 = wr[og * F_ + f + 1];
                const float wv2 = wr[og * F_ + f + 2];
                #pragma unroll
                for (int p = 0; p < 4; ++p) {
                    float v0 = __builtin_fabsf(xw[p + 0] - wv0);
                    float v1 = __builtin_fabsf(xw[p + 1] - wv1);
                    float v2 = __builtin_fabsf(xw[p + 2] - wv2);
                    float mm = m[og][p];
                    mm = fmaxf(fmaxf(mm, v0), v1);   // -> v_max3
                    m[og][p] = fmaxf(mm, v2);
                }
            }
        }
    }

    // ---- c-split combine: groups 1..3 publish, wave 0 reduces + stores ----
    if (g > 0) {
        #pragma unroll
        for (int og = 0; og < 2; ++og)
            *reinterpret_cast<float4*>(&sc[g - 1][og][hl][w0]) =
                make_float4(m[og][0], m[og][1], m[og][2], m[og][3]);
    }
    __syncthreads();

    if (g == 0) {
        #pragma unroll
        for (int og = 0; og < 2; ++og) {
            float4 a = *reinterpret_cast<const float4*>(&sc[0][og][hl][w0]);
            float4 b = *reinterpret_cast<const float4*>(&sc[1][og][hl][w0]);
            float4 d = *reinterpret_cast<const float4*>(&sc[2][og][hl][w0]);
            const float bv = bias[o0 + og];
            float4 r;
            r.x = fmaxf(fmaxf(fmaxf(m[og][0], a.x), b.x), d.x) + bv;
            r.y = fmaxf(fmaxf(fmaxf(m[og][1], a.y), b.y), d.y) + bv;
            r.z = fmaxf(fmaxf(fmaxf(m[og][2], a.z), b.z), d.z) + bv;
            r.w = fmaxf(fmaxf(fmaxf(m[og][3], a.w), b.w), d.w) + bv;
            float* dst = out + ((size_t)(n * O_ + o0 + og) * (H_ * W_))
                             + (h0 + hl) * W_ + w0;
            *reinterpret_cast<float4*>(dst) = r;
        }
    }
}

extern "C" void kernel_launch(void* const* d_in, const int* in_sizes, int n_in,
                              void* d_out, int out_size, void* d_ws, size_t ws_size,
                              hipStream_t stream) {
    const float* x  = (const float*)d_in[0];
    const float* w  = (const float*)d_in[1];
    const float* b  = (const float*)d_in[2];
    float* out      = (float*)d_out;

    dim3 grid(O_ / 2, H_ / HT, N_);   // 32 x 4 x 8 = 1024 blocks
    dim3 block(256);
    hipLaunchKernelGGL(normdist_kernel, grid, block, 0, stream, x, w, b, out);
}